// Round 1
// baseline (608.336 us; speedup 1.0000x reference)
//
#include <hip/hip_runtime.h>
#include <cstdint>
#include <cstddef>

// CTC loss forward (mean over batch of loss/target_len), MI355X gfx950.
// Shapes fixed by the reference: log_probs [T=256, B=64, C=8000] f32 (already
// log-softmaxed), targets [B, L=32] i32, input_lengths [B] i32, target_lengths
// [B] i32. Output: 1 float.
//
// v2 design: one 256-thread block per batch element.
//   Phase 1: cooperative emission gather. Thread t (0..255 == T exactly)
//            gathers the 33 distinct emissions for its timestep (32 label
//            columns + 1 blank) into LDS s_em[t][33]. 33 independent loads
//            per thread, fully unrolled -> massive memory-level parallelism;
//            the scattered-gather latency that dominated v1 (~2300 cy/step
//            exposed per serial DP step) is paid once, in parallel.
//   Phase 2: wave 0 runs the serial DP (lane = CTC state s, S = 65; lane 63
//            also carries s=64). Emissions now come from conflict-free
//            ds_read_b32 (odd lanes hit 32 distinct banks, even lanes are a
//            single broadcast address), prefetched one step ahead, so the
//            loop runs at the ~110 cy/step VALU+shfl dependency floor.
// Alpha is kept in the log2 domain (alpha2 = alpha * log2e) so each step
// needs no extra muls around v_exp_f32/v_log_f32.

#define TMAX  256
#define BATCH 64
#define CNUM  8000
#define LMAX  32
#define SDIM  65
#define LOG2E 1.44269504088896340736f
#define LN2   0.69314718055994530942f
#define NEG2  (-1.0e9f * LOG2E)   // reference NEG = -1e9, in log2 domain

// gfx950 hardware base-2 transcendentals (HIP has no __exp2f/__log2f device
// intrinsics; the CUDA spellings collide with glibc math.h host decls).
__device__ __forceinline__ float hexp2(float x) { return __builtin_amdgcn_exp2f(x); }
__device__ __forceinline__ float hlog2(float x) { return __builtin_amdgcn_logf(x); }

__device__ __forceinline__ float lae3_log2(float a, float b, float c) {
    // log2(2^a + 2^b + 2^c), inputs in log2 domain
    float m = fmaxf(fmaxf(a, b), c);                 // v_max3
    float r = hexp2(a - m) + hexp2(b - m) + hexp2(c - m);
    return m + hlog2(r);
}

__global__ __launch_bounds__(256) void ctc_dp(
    const float* __restrict__ lp, const int* __restrict__ targets,
    const int* __restrict__ in_len, const int* __restrict__ tg_len,
    float* __restrict__ partial)
{
    const int b   = blockIdx.x;
    const int tid = threadIdx.x;
    const int Lb  = tg_len[b];
    const int Tb  = in_len[b];

    // cols 0..31: emission of odd state s=2k+1 (label k); col 32: blank.
    // 256*33*4 = 33792 B. Stride 33 floats: for fixed k, bank(t) = (t+k)%32
    // -> conflict-free writes; DP reads hit 32 distinct banks + 1 broadcast.
    __shared__ float s_em[TMAX][LMAX + 1];

    // ---- Phase 1: cooperative gather of all emissions into LDS ----
    {
        const int t = tid;   // blockDim.x == TMAX == 256 exactly
        const float* rowbase = lp + (size_t)t * (size_t)(BATCH * CNUM)
                                  + (size_t)b * CNUM;
        s_em[t][LMAX] = rowbase[0];                 // blank emission
        #pragma unroll
        for (int k = 0; k < LMAX; ++k) {
            // targets[b*LMAX+k] is wave-uniform -> scalar load; masked labels
            // fall back to blank (label 0), an L1 hit after the blank load.
            int lab = (k < Lb) ? targets[b * LMAX + k] : 0;
            s_em[t][k] = rowbase[lab];
        }
    }
    __syncthreads();
    if (tid >= 64) return;   // waves 1..3 done; wave 0 runs the DP alone

    // ---- Phase 2: serial DP over t, lane = CTC state s ----
    const int lane = tid;

    int  label = 0;
    bool skip  = false;
    if (lane & 1) {
        int k = lane >> 1;
        label = (k < Lb) ? targets[b * LMAX + k] : 0;
        int prev = (k >= 1) ? ((k - 1 < Lb) ? targets[b * LMAX + (k - 1)] : 0) : -1;
        skip = (label != 0) && (label != prev);
    }
    const bool use2 = skip && (lane >= 2);  // s<2 has no s-2 predecessor

    // Per-lane LDS column: odd state s -> col s>>1; even (blank) -> col 32.
    const int col = (lane & 1) ? (lane >> 1) : LMAX;

    // t = 0 init (alpha in log2 domain)
    float em0 = s_em[0][col];
    float a   = NEG2;
    if (lane == 0)            a = em0 * LOG2E;
    if (lane == 1 && Lb > 0)  a = em0 * LOG2E;
    float a64 = NEG2;                       // state s=64 (valid on lane 63)

    const int steps = Tb - 1;               // >= 128 per setup
    float emc = s_em[1][col];               // prefetched emission for t=1
    for (int t = 1; t <= steps; ++t) {
        int tn = (t < TMAX - 1) ? (t + 1) : (TMAX - 1);
        float emn = s_em[tn][col];          // prefetch t+1, hidden under chain

        float em2  = emc * LOG2E;
        // blank emission for s=64 == lane 0's emission (lane 0 is blank col)
        float em2b = __uint_as_float(
            __builtin_amdgcn_readfirstlane(__float_as_uint(em2)));

        float am1 = __shfl_up(a, 1, 64);
        float am2 = __shfl_up(a, 2, 64);
        am1 = (lane >= 1) ? am1 : NEG2;
        float am2p = use2 ? am2 : NEG2;

        // s=64 update from OLD a64 and OLD a[63] (own value on lane 63);
        // computed on all lanes, only lane 63's result is meaningful.
        float m64  = fmaxf(a64, a);
        float r64  = hexp2(a64 - m64) + hexp2(a - m64);
        float a64n = m64 + hlog2(r64) + em2b;

        a   = lae3_log2(a, am1, am2p) + em2;
        a64 = a64n;
        emc = emn;
    }

    // Final readout via shuffles (single wave -> no barrier needed).
    int iB = 2 * Lb;
    int iC = iB - 1; if (iC < 0) iC = 0;                 // iC <= 63 always
    float vB = (iB < 64) ? __shfl(a, iB, 64) : __shfl(a64, 63, 64);
    float vC = __shfl(a, iC, 64);

    if (lane == 0) {
        float tot2;
        if (Lb > 0) {
            float m = fmaxf(vB, vC);
            tot2 = m + hlog2(hexp2(vB - m) + hexp2(vC - m));
        } else {
            tot2 = vB;
        }
        float loss = -(tot2 * LN2);                  // back to natural log
        float sl   = (Lb > 0) ? (float)Lb : 1.0f;
        partial[b] = loss / sl;
    }
}

__global__ __launch_bounds__(64) void ctc_reduce(
    const float* __restrict__ partial, float* __restrict__ out)
{
    float v = partial[threadIdx.x];
    #pragma unroll
    for (int off = 32; off > 0; off >>= 1) v += __shfl_xor(v, off, 64);
    if (threadIdx.x == 0) out[0] = v * (1.0f / BATCH);
}

extern "C" void kernel_launch(void* const* d_in, const int* in_sizes, int n_in,
                              void* d_out, int out_size, void* d_ws, size_t ws_size,
                              hipStream_t stream) {
    const float* lp = (const float*)d_in[0];
    const int*   tg = (const int*)d_in[1];
    const int*   il = (const int*)d_in[2];
    const int*   tl = (const int*)d_in[3];
    float* partial  = (float*)d_ws;        // 64 floats; fully overwritten each call

    ctc_dp<<<dim3(BATCH), dim3(256), 0, stream>>>(lp, tg, il, tl, partial);
    ctc_reduce<<<dim3(1), dim3(64), 0, stream>>>(partial, (float*)d_out);
}

// Round 2
// 602.759 us; speedup vs baseline: 1.0093x; 1.0093x over previous
//
#include <hip/hip_runtime.h>
#include <cstdint>
#include <cstddef>

// CTC loss forward (mean over batch of loss/target_len), MI355X gfx950.
// Shapes fixed by the reference: log_probs [T=256, B=64, C=8000] f32 (already
// log-softmaxed), targets [B, L=32] i32, input_lengths [B] i32, target_lengths
// [B] i32. Output: 1 float.
//
// v3 design: one 256-thread block per batch element.
//   Phase 1: cooperative emission gather (thread t of 0..255 pulls the 33
//            distinct emissions for its timestep into LDS, pre-scaled by
//            log2(e)).
//   Phase 2: wave 0 runs the serial DP in PAIR LAYOUT: lane k holds states
//            2k (blank/even) and 2k+1 (label/odd), k = 0..32. Both state
//            updates need exactly ONE cross-lane value, a_odd[k-1], which is
//            fetched with a DPP wave_shr:1 (VALU pipe, ~4-8 cy dependent
//            latency) instead of ds_bpermute (~120 cy LDS-unit latency) --
//            the bpermute at the head of each of the 255 serial steps was
//            the dominant term of the loop's dependency chain. The DPP
//            `old` operand injects the NEG boundary value at lane 0 for free.
// Alpha is kept in the log2 domain (alpha2 = alpha * log2e); emissions are
// pre-scaled in phase 1 so the inner loop has no multiplies on the chain.

#define TMAX  256
#define BATCH 64
#define CNUM  8000
#define LMAX  32
#define LOG2E 1.44269504088896340736f
#define LN2   0.69314718055994530942f
#define NEG2  (-1.0e9f * LOG2E)   // reference NEG = -1e9, in log2 domain

// gfx950 hardware base-2 transcendentals (HIP has no __exp2f/__log2f device
// intrinsics; the CUDA spellings collide with glibc math.h host decls).
__device__ __forceinline__ float hexp2(float x) { return __builtin_amdgcn_exp2f(x); }
__device__ __forceinline__ float hlog2(float x) { return __builtin_amdgcn_logf(x); }

// lane i receives x from lane i-1; lane 0 receives `fill`.
// DPP ctrl 0x138 = wave_shr:1 (gfx9 family; valid on gfx950). bound_ctrl=0
// keeps the `old` operand where the source lane is invalid (lane 0).
__device__ __forceinline__ float dpp_shr1(float x, float fill) {
    int v = __builtin_amdgcn_update_dpp(
        __float_as_int(fill), __float_as_int(x), 0x138, 0xf, 0xf, false);
    return __int_as_float(v);
}

__global__ __launch_bounds__(256) void ctc_dp(
    const float* __restrict__ lp, const int* __restrict__ targets,
    const int* __restrict__ in_len, const int* __restrict__ tg_len,
    float* __restrict__ partial)
{
    const int b   = blockIdx.x;
    const int tid = threadIdx.x;
    const int Lb  = tg_len[b];
    const int Tb  = in_len[b];

    // cols 0..31: emission of odd state s=2k+1 (label k); col 32: blank.
    // 256*33*4 = 33792 B. Stride 33 floats -> for fixed col the bank walks
    // with t; DP reads (lanes 0..31 -> cols 0..31 of one row) hit 32 distinct
    // banks; the blank read is a same-address broadcast.
    __shared__ float s_em[TMAX][LMAX + 1];

    // ---- Phase 1: cooperative gather of all emissions into LDS ----
    {
        const int t = tid;   // blockDim.x == TMAX == 256 exactly
        const float* rowbase = lp + (size_t)t * (size_t)(BATCH * CNUM)
                                  + (size_t)b * CNUM;
        s_em[t][LMAX] = rowbase[0] * LOG2E;         // blank emission
        #pragma unroll
        for (int k = 0; k < LMAX; ++k) {
            // targets[b*LMAX+k] is block-uniform -> scalar load; masked
            // labels fall back to blank (label 0), an L1 hit.
            int lab = (k < Lb) ? targets[b * LMAX + k] : 0;
            s_em[t][k] = rowbase[lab] * LOG2E;
        }
    }
    __syncthreads();
    if (tid >= 64) return;   // waves 1..3 done; wave 0 runs the DP alone

    // ---- Phase 2: serial DP over t; lane k holds states 2k and 2k+1 ----
    const int lane = tid;

    // skip flag for odd state 2k+1: label_k != 0 && label_k != label_{k-1}
    // (k=0 compares against ext[-1] = -1 -> skip iff label != 0).
    int lab_k = (lane < Lb) ? targets[b * LMAX + lane] : 0;
    int lab_p = (lane >= 1)
                    ? ((lane - 1 < Lb) ? targets[b * LMAX + (lane - 1)] : 0)
                    : -1;
    const bool skip = (lab_k != 0) && (lab_k != lab_p);

    const int colo = (lane < LMAX) ? lane : LMAX;   // odd-state emission col

    // t = 0 init (alpha in log2 domain; emissions pre-scaled)
    float ae = NEG2, ao = NEG2;                     // states 2k, 2k+1
    if (lane == 0) {
        ae = s_em[0][LMAX];                         // s=0: blank
        if (Lb > 0) ao = s_em[0][0];                // s=1: first label
    }

    const int steps = Tb - 1;                       // >= 128 per setup
    float eo_c = s_em[1][colo];                     // prefetched t=1
    float eb_c = s_em[1][LMAX];
    for (int t = 1; t <= steps; ++t) {
        int tn = (t < TMAX - 1) ? (t + 1) : (TMAX - 1);
        float eo_n = s_em[tn][colo];                // prefetch t+1 (off-chain)
        float eb_n = s_em[tn][LMAX];

        float po  = dpp_shr1(ao, NEG2);             // a_odd[k-1]; NEG2 at k=0
        float pos = skip ? po : NEG2;

        // even state 2k: lae(ae, po) + blank em   (s=64 is lane 32's ae)
        float me = fmaxf(ae, po);
        float re = hexp2(ae - me) + hexp2(po - me);
        float ne = me + hlog2(re) + eb_c;

        // odd state 2k+1: lae(ao, ae_old, pos) + label em
        float mo = fmaxf(fmaxf(ao, ae), pos);
        float ro = hexp2(ao - mo) + hexp2(ae - mo) + hexp2(pos - mo);
        float no = mo + hlog2(ro) + eo_c;

        ae = ne; ao = no;
        eo_c = eo_n; eb_c = eb_n;
    }

    // Final readout: v_blank = state 2Lb = ae@lane Lb; v_char = state 2Lb-1
    // = ao@lane Lb-1 (Lb > 0 always per setup, but guard anyway).
    float vB = __shfl(ae, Lb, 64);
    float vC = __shfl(ao, (Lb > 0) ? (Lb - 1) : 0, 64);

    if (lane == 0) {
        float tot2;
        if (Lb > 0) {
            float m = fmaxf(vB, vC);
            tot2 = m + hlog2(hexp2(vB - m) + hexp2(vC - m));
        } else {
            tot2 = vB;
        }
        float loss = -(tot2 * LN2);                  // back to natural log
        float sl   = (Lb > 0) ? (float)Lb : 1.0f;
        partial[b] = loss / sl;
    }
}

__global__ __launch_bounds__(64) void ctc_reduce(
    const float* __restrict__ partial, float* __restrict__ out)
{
    float v = partial[threadIdx.x];
    #pragma unroll
    for (int off = 32; off > 0; off >>= 1) v += __shfl_xor(v, off, 64);
    if (threadIdx.x == 0) out[0] = v * (1.0f / BATCH);
}

extern "C" void kernel_launch(void* const* d_in, const int* in_sizes, int n_in,
                              void* d_out, int out_size, void* d_ws, size_t ws_size,
                              hipStream_t stream) {
    const float* lp = (const float*)d_in[0];
    const int*   tg = (const int*)d_in[1];
    const int*   il = (const int*)d_in[2];
    const int*   tl = (const int*)d_in[3];
    float* partial  = (float*)d_ws;        // 64 floats; fully overwritten each call

    ctc_dp<<<dim3(BATCH), dim3(256), 0, stream>>>(lp, tg, il, tl, partial);
    ctc_reduce<<<dim3(1), dim3(64), 0, stream>>>(partial, (float*)d_out);
}